// Round 13
// baseline (4458.648 us; speedup 1.0000x reference)
//
#include <hip/hip_runtime.h>
#include <math.h>

// ---------------------------------------------------------------------------
// Disentangler: 32 component-MLPs over sampled token rows + masked seg-pool.
// Round-13: occupancy play. 256x128 block / 4 waves of 128x64, SINGLE-buffered
// A (glds, pre-swizzled bf16) and B (fused W-transpose: fp32 row loads -> reg
// cvt -> swizzled ds_write). 48 KB LDS -> 3 blocks/CU (m97 regime: per-block
// stage-drain hidden by co-resident blocks). Gate vmcnt BEFORE the barrier
// (correct cross-wave ordering). Stride-257 gemm2 seg-reduce. T1 swizzle.
// ---------------------------------------------------------------------------

typedef __attribute__((ext_vector_type(8))) short bf16x8;
typedef __attribute__((ext_vector_type(4))) short s16x4;
typedef __attribute__((ext_vector_type(4))) float f32x4;
typedef unsigned int u32;

constexpr int TT    = 16;
constexpr int TOKN  = 4096;
constexpr int DD    = 2048;
constexpr int HH    = 2048;
constexpr int CC    = 1024;
constexpr int LL    = 1000;
constexpr int NCOMP = 32;
constexpr int MP    = 1024;
constexpr int BMX = 256, BNX = 128;
constexpr int MTX  = MP / BMX;    // 4 m-tiles
constexpr int NT1 = HH / BNX;     // 16 n-tiles (gemm1)
constexpr int NT2 = CC / BNX;     // 8  n-tiles (gemm2)
constexpr int NT  = 2048 / 64;    // 32 K-tiles (K = 2048 both GEMMs)

__device__ __forceinline__ short f2bf(float f) {
  __bf16 h = (__bf16)f;
  return *reinterpret_cast<short*>(&h);
}
// Row swizzle (period 64): data-granule g of a 64-elem chunk lives at slot
// g ^ swz(row). Identical layout in Ab, h, and the LDS tiles.
__device__ __forceinline__ int swz(int row) {
  return (row & 7) ^ ((row >> 3) & 7);
}
__device__ __forceinline__ int sw(int row, int gran) {   // short offset
  return (row << 6) + ((gran ^ swz(row)) << 3);
}
__device__ __forceinline__ void gl_lds16(const void* g, void* l) {
  __builtin_amdgcn_global_load_lds(
      (const __attribute__((address_space(1))) u32*)g,
      (__attribute__((address_space(3))) u32*)l, 16, 0, 0);
}

// --------------------------- dedup ----------------------------------------
__global__ void dedup_kernel(const int* __restrict__ ridx,
                             unsigned* __restrict__ bitmap,
                             float* __restrict__ keepf) {
  int comp = blockIdx.x;
  for (int l = threadIdx.x; l < MP; l += 256) {
    float kv = 0.0f;
    if (l < LL) {
      int r = ridx[comp * LL + l];
      unsigned bit = 1u << (r & 31);
      unsigned old = atomicOr(&bitmap[(comp << 10) + (r >> 5)], bit);
      kv = (old & bit) ? 0.0f : 1.0f;
    }
    keepf[(comp << 10) + l] = kv;
  }
}

// --------------------------- gather: x rows -> pre-swizzled bf16 -----------
__global__ __launch_bounds__(256) void gather_kernel(
    const float* __restrict__ x, const int* __restrict__ ridx,
    short* __restrict__ Ab) {
  int bid = blockIdx.x;
  int comp = bid >> 7, rgrp = bid & 127;
  int t = threadIdx.x;
  int tr = t >> 5, tn = t & 31;
  int m = rgrp * 8 + tr;
  int mi = m < LL ? m : LL - 1;
  int r = ridx[comp * LL + mi];
  int tokoff = comp >= 16 ? TOKN / 2 : 0;
  const float* src = x + ((size_t)(r >> 11) * TOKN + (r & 2047) + tokoff) * DD;
  short* drow = Ab + ((size_t)(comp * MP + m)) * DD;
  int s_m = swz(m);
#pragma unroll
  for (int i = 0; i < 8; ++i) {
    int gi = tn + 32 * i;
    float4 f0 = *reinterpret_cast<const float4*>(src + gi * 8);
    float4 f1 = *reinterpret_cast<const float4*>(src + gi * 8 + 4);
    bf16x8 pk;
    pk[0]=f2bf(f0.x); pk[1]=f2bf(f0.y); pk[2]=f2bf(f0.z); pk[3]=f2bf(f0.w);
    pk[4]=f2bf(f1.x); pk[5]=f2bf(f1.y); pk[6]=f2bf(f1.z); pk[7]=f2bf(f1.w);
    int c = gi >> 3, g = gi & 7;
    *reinterpret_cast<bf16x8*>(&drow[c * 64 + ((g ^ s_m) << 3)]) = pk;
  }
}

// --------------------------- shared K-loop (single-buffered, 48 KB) --------
// LDS (shorts): Abuf[16384] @0 (256 rows x 64k), Bbuf[8192] @16384.
// Iter t: compute(t); barrier; bwrite B(t+1) [regs]; aglds A(t+1);
// bload B(t+2); lgkm(0); vmcnt(8 | 0 at tail) -> own aglds drained BEFORE
// barrier (cross-wave safe); barrier. Per-block drain hidden by 3 blocks/CU.
template<int LDW>
__device__ __forceinline__ void kloop(
    const short* __restrict__ aBase,   // bf16 pre-swizzled rows, stride 2048
    const float* __restrict__ wBase,   // fp32 W [k][LDW] at col offset nt*BNX
    short* sm, f32x4 (&acc)[8][4],
    int wm, int wn, int lr, int lg, int tid) {
  const short* aSrc0 = aBase + (size_t)(tid >> 3) * 2048 + (tid & 7) * 8;
  int ldsA0 = tid * 8;
  int tn = tid & 31, tkb = tid >> 5, bn0 = tn * 4;
  const float* wCol = wBase + bn0;

  float4 brB[8];

  auto aglds = [&](int t) {
#pragma unroll
    for (int q = 0; q < 8; ++q)
      gl_lds16(aSrc0 + (size_t)q * 65536 + t * 64, sm + ldsA0 + q * 2048);
  };
  auto bload = [&](int t) {
    const float* bb = wCol + (size_t)(t * 64 + tkb * 8) * LDW;
#pragma unroll
    for (int i = 0; i < 8; ++i)
      brB[i] = *reinterpret_cast<const float4*>(bb + (size_t)i * LDW);
  };
  auto bwrite = [&]() {
    short* Bs = sm + 16384;
#pragma unroll
    for (int j = 0; j < 4; ++j) {
      bf16x8 pk;
#pragma unroll
      for (int i = 0; i < 8; ++i) pk[i] = f2bf((&brB[i].x)[j]);
      *reinterpret_cast<bf16x8*>(&Bs[sw(bn0 + j, tkb)]) = pk;
    }
  };
  auto compute = [&]() {
    const short* A = sm;
    const short* B = sm + 16384;
#pragma unroll
    for (int kk = 0; kk < 2; ++kk) {
      bf16x8 af[8], bfr[4];
#pragma unroll
      for (int i = 0; i < 8; ++i)
        af[i] = *reinterpret_cast<const bf16x8*>(&A[sw(wm + i * 16 + lr, kk * 4 + lg)]);
#pragma unroll
      for (int j = 0; j < 4; ++j)
        bfr[j] = *reinterpret_cast<const bf16x8*>(&B[sw(wn + j * 16 + lr, kk * 4 + lg)]);
      __builtin_amdgcn_s_setprio(1);
#pragma unroll
      for (int i = 0; i < 8; ++i)
#pragma unroll
        for (int j = 0; j < 4; ++j)
          acc[i][j] = __builtin_amdgcn_mfma_f32_16x16x32_bf16(af[i], bfr[j], acc[i][j], 0, 0, 0);
      __builtin_amdgcn_s_setprio(0);
    }
  };

  // prologue: B(0) regs -> Bbuf; A(0) glds; B(1) regs; full drain; barrier.
  bload(0);
  aglds(0);
  bwrite();                 // compiler waits bload(0) (aglds may overlap)
  bload(1);
  asm volatile("s_waitcnt vmcnt(0) lgkmcnt(0)" ::: "memory");
  __builtin_amdgcn_s_barrier();

#pragma unroll 1
  for (int t = 0; t < NT; ++t) {
    compute();
    __builtin_amdgcn_s_barrier();          // all waves done reading A(t), B(t)
    if (t + 1 < NT) {
      bwrite();                            // B(t+1) -> Bbuf (regs valid)
      aglds(t + 1);                        // A(t+1) -> Abuf (readers done)
      if (t + 2 < NT) {
        bload(t + 2);                      // newest 8: stays in flight
        asm volatile("s_waitcnt lgkmcnt(0)" ::: "memory");
        asm volatile("s_waitcnt vmcnt(8)" ::: "memory");   // aglds(t+1) done
      } else {
        asm volatile("s_waitcnt vmcnt(0) lgkmcnt(0)" ::: "memory");
      }
      __builtin_amdgcn_s_barrier();        // cross-wave: staging visible
    }
  }
}

// --------------------------- GEMM1: h = gelu(x_sel @ W1 + b1) --------------
__global__ __launch_bounds__(256, 3) void gemm1_kernel(
    const float* __restrict__ nW1, const float* __restrict__ nb1,
    const float* __restrict__ eW1, const float* __restrict__ eb1,
    const short* __restrict__ Ab, short* __restrict__ hbuf) {
  __shared__ short smem[24576];   // 48 KB -> 3 blocks/CU

  constexpr int NWG = NCOMP * MTX * NT1;   // 2048
  constexpr int CPX = NWG / 8;
  int b0 = blockIdx.x;
  int lb = (b0 & 7) * CPX + (b0 >> 3);     // XCD-chunked (T1), bijective
  int comp = lb / (MTX * NT1);
  int rem  = lb % (MTX * NT1);
  int mt = rem / NT1, nt = rem % NT1;
  bool isEdge = comp >= 16;
  int k16 = isEdge ? comp - 16 : comp;
  const float* W1 = (isEdge ? eW1 : nW1) + (size_t)k16 * DD * HH;
  const float* b1 = (isEdge ? eb1 : nb1) + (size_t)k16 * HH;

  int tid = threadIdx.x, lane = tid & 63, wid = tid >> 6;
  int wm = (wid >> 1) << 7, wn = (wid & 1) << 6;   // 2x2 waves of 128x64
  int lr = lane & 15, lg = lane >> 4;

  f32x4 acc[8][4] = {};
  kloop<HH>(Ab + ((size_t)(comp * MP + mt * BMX)) * DD,
            W1 + nt * BNX, smem, acc, wm, wn, lr, lg, tid);

  // epilogue: +b1, exact gelu; two 128-row phases through a 33 KB Cs
  // (stride 132), then coalesced PRE-SWIZZLED bf16 h store.
  __builtin_amdgcn_s_barrier();
  short* Cs = smem;                        // 128*132 = 16896 shorts (33 KB)
  const float* b1p = b1 + nt * BNX;
#pragma unroll 1
  for (int p = 0; p < 2; ++p) {
    if ((wm >> 7) == p) {                  // waves owning rows p*128..+127
#pragma unroll
      for (int i = 0; i < 8; ++i)
#pragma unroll
        for (int j = 0; j < 4; ++j) {
          int nl = wn + j * 16 + lr;
          float bias = b1p[nl];
#pragma unroll
          for (int rr = 0; rr < 4; ++rr) {
            int r = i * 16 + lg * 4 + rr;  // 0..127 within phase
            float v = acc[i][j][rr] + bias;
            float ge = 0.5f * v * (1.0f + erff(v * 0.70710678118654752f));
            Cs[r * 132 + nl] = f2bf(ge);
          }
        }
    }
    __syncthreads();
    short* hrow = hbuf + ((size_t)(comp * MP + mt * BMX + p * 128)) * HH;
#pragma unroll
    for (int q = 0; q < 16; ++q) {
      int gl = q * 256 + tid;
      int r = gl >> 5, gg = gl & 31;       // 32 4-short granules per row
      s16x4 v = *reinterpret_cast<const s16x4*>(&Cs[r * 132 + gg * 4]);
      int dst = (nt * 2 + (gg >> 4)) * 64 + ((((gg >> 1) & 7) ^ swz(r)) << 3) + (gg & 1) * 4;
      *reinterpret_cast<s16x4*>(&hrow[(size_t)r * HH + dst]) = v;
    }
    __syncthreads();
  }
}

// --------------------------- GEMM2: o = h @ W2 + b2, masked seg-reduce -----
__global__ __launch_bounds__(256, 3) void gemm2_kernel(
    const short* __restrict__ hbuf, const int* __restrict__ ridx,
    const float* __restrict__ nW2, const float* __restrict__ nb2,
    const float* __restrict__ eW2, const float* __restrict__ eb2,
    const float* __restrict__ keepf, float* __restrict__ partial) {
  __shared__ short smem[24576];   // 48 KB

  constexpr int NWG = NCOMP * MTX * NT2;   // 1024
  constexpr int CPX = NWG / 8;
  int b0 = blockIdx.x;
  int lb = (b0 & 7) * CPX + (b0 >> 3);
  int comp = lb / (MTX * NT2);
  int rem  = lb % (MTX * NT2);
  int mt = rem / NT2, nt = rem % NT2;
  bool isEdge = comp >= 16;
  int k16 = isEdge ? comp - 16 : comp;
  const float* W2 = (isEdge ? eW2 : nW2) + (size_t)k16 * HH * CC;
  const float* b2 = (isEdge ? eb2 : nb2) + (size_t)k16 * CC;

  int tid = threadIdx.x, lane = tid & 63, wid = tid >> 6;
  int wm = (wid >> 1) << 7, wn = (wid & 1) << 6;
  int lr = lane & 15, lg = lane >> 4;

  f32x4 acc[8][4] = {};
  kloop<CC>(hbuf + ((size_t)(comp * MP + mt * BMX)) * HH,
            W2 + nt * BNX, smem, acc, wm, wn, lr, lg, tid);

  // epilogue: (+b2) * keep, seg-reduce 256 rows by timestamp.
  // part stride 257 (257%32==1): t spreads across banks; no deterministic
  // same-bank atomicAdd pileups.
  __builtin_amdgcn_s_barrier();
  float* part = (float*)smem;                     // 16*257 floats = 16.4 KB
  int*   tarr = (int*)((char*)smem + 16640);      // 256 ints
  float* karr = (float*)((char*)smem + 17664);    // 256 floats
  if (tid < BMX) {
    int mglob = mt * BMX + tid;
    int mi = mglob < LL ? mglob : LL - 1;
    int r2 = ridx[comp * LL + mi];
    tarr[tid] = r2 >> 11;
    karr[tid] = keepf[(comp << 10) + mglob];      // 0 for padded/dup rows
  }
  for (int e = tid; e < TT * 257; e += 256) part[e] = 0.0f;
  __syncthreads();
  const float* b2p = b2 + nt * BNX;
#pragma unroll
  for (int i = 0; i < 8; ++i)
#pragma unroll
    for (int j = 0; j < 4; ++j) {
      int nl = wn + j * 16 + lr;
      float bias = b2p[nl];
#pragma unroll
      for (int rr = 0; rr < 4; ++rr) {
        int ml = wm + i * 16 + lg * 4 + rr;
        float v = (acc[i][j][rr] + bias) * karr[ml];
        atomicAdd(&part[tarr[ml] * 257 + nl], v);
      }
    }
  __syncthreads();
  float* pout = partial + ((size_t)(comp * MTX + mt)) * TT * CC + nt * BNX;
  for (int e = tid; e < TT * BNX; e += 256) {
    int t2 = e >> 7, c = e & 127;
    pout[(size_t)t2 * CC + c] = part[t2 * 257 + c];
  }
}

// --------------------------- final reduce over m-tiles ---------------------
__global__ void reduce_kernel(const float* __restrict__ partial,
                              float* __restrict__ out) {
  int idx = blockIdx.x * 256 + threadIdx.x;
  int c    = idx & (CC - 1);
  int comp = (idx >> 10) & (NCOMP - 1);
  int t    = idx >> 15;
  float s = 0.0f;
#pragma unroll
  for (int mt = 0; mt < MTX; ++mt)
    s += partial[(((size_t)(comp * MTX + mt)) * TT + t) * CC + c];
  out[idx] = s * (1.0f / 4096.0f);
}

// ---------------------------------------------------------------------------
extern "C" void kernel_launch(void* const* d_in, const int* in_sizes, int n_in,
                              void* d_out, int out_size, void* d_ws, size_t ws_size,
                              hipStream_t stream) {
  const float* x    = (const float*)d_in[0];
  const int*   ridx = (const int*)d_in[3];
  const float* nW1  = (const float*)d_in[4];
  const float* nb1  = (const float*)d_in[5];
  const float* nW2  = (const float*)d_in[6];
  const float* nb2  = (const float*)d_in[7];
  const float* eW1  = (const float*)d_in[8];
  const float* eb1  = (const float*)d_in[9];
  const float* eW2  = (const float*)d_in[10];
  const float* eb2  = (const float*)d_in[11];
  float* out = (float*)d_out;

  // ws: [h 134MB][bitmap][keep][partial 8.4MB][Ab 134MB]  ~277 MB
  const size_t H_B   = (size_t)NCOMP * MP * HH * 2;
  const size_t BMP_B = (size_t)NCOMP * 1024 * 4;
  const size_t KP_B  = (size_t)NCOMP * 1024 * 4;
  const size_t PRT_B = (size_t)NCOMP * MTX * TT * CC * 4;
  const size_t base  = H_B + BMP_B + KP_B + PRT_B;

  char* ws = (char*)d_ws;
  short* hbuf      = (short*)ws;
  unsigned* bitmap = (unsigned*)(ws + H_B);
  float* keepf     = (float*)(ws + H_B + BMP_B);
  float* partial   = (float*)(ws + H_B + BMP_B + KP_B);
  short* Ab        = (short*)(ws + base);

  hipMemsetAsync(bitmap, 0, BMP_B, stream);
  dedup_kernel<<<NCOMP, 256, 0, stream>>>(ridx, bitmap, keepf);
  gather_kernel<<<NCOMP * 128, 256, 0, stream>>>(x, ridx, Ab);
  gemm1_kernel<<<NCOMP * MTX * NT1, 256, 0, stream>>>(nW1, nb1, eW1, eb1, Ab, hbuf);
  gemm2_kernel<<<NCOMP * MTX * NT2, 256, 0, stream>>>(hbuf, ridx, nW2, nb2, eW2, eb2, keepf, partial);
  reduce_kernel<<<out_size / 256, 256, 0, stream>>>(partial, out);
}

// Round 14
// 838.933 us; speedup vs baseline: 5.3147x; 5.3147x over previous
//
#include <hip/hip_runtime.h>
#include <math.h>

// ---------------------------------------------------------------------------
// Disentangler: 32 component-MLPs over sampled token rows + masked seg-pool.
// Round-14 (= r13 minus the spill): 256x128 block / 4 waves of 128x64,
// SINGLE-buffered A (glds, pre-swizzled bf16) + B (fused W-transpose),
// 48 KB LDS -> natural 3 blocks/CU. __launch_bounds__(256,2) (NOT 3 —
// r13's (256,3) capped VGPR at 84 and spilled the 128-reg accumulator to
// scratch: 6 GB WRITE_SIZE, 6.5x slowdown). Stride-257 gemm2 seg-reduce.
// ---------------------------------------------------------------------------

typedef __attribute__((ext_vector_type(8))) short bf16x8;
typedef __attribute__((ext_vector_type(4))) short s16x4;
typedef __attribute__((ext_vector_type(4))) float f32x4;
typedef unsigned int u32;

constexpr int TT    = 16;
constexpr int TOKN  = 4096;
constexpr int DD    = 2048;
constexpr int HH    = 2048;
constexpr int CC    = 1024;
constexpr int LL    = 1000;
constexpr int NCOMP = 32;
constexpr int MP    = 1024;
constexpr int BMX = 256, BNX = 128;
constexpr int MTX  = MP / BMX;    // 4 m-tiles
constexpr int NT1 = HH / BNX;     // 16 n-tiles (gemm1)
constexpr int NT2 = CC / BNX;     // 8  n-tiles (gemm2)
constexpr int NT  = 2048 / 64;    // 32 K-tiles (K = 2048 both GEMMs)

__device__ __forceinline__ short f2bf(float f) {
  __bf16 h = (__bf16)f;
  return *reinterpret_cast<short*>(&h);
}
// Row swizzle (period 64): data-granule g of a 64-elem chunk lives at slot
// g ^ swz(row). Identical layout in Ab, h, and the LDS tiles.
__device__ __forceinline__ int swz(int row) {
  return (row & 7) ^ ((row >> 3) & 7);
}
__device__ __forceinline__ int sw(int row, int gran) {   // short offset
  return (row << 6) + ((gran ^ swz(row)) << 3);
}
__device__ __forceinline__ void gl_lds16(const void* g, void* l) {
  __builtin_amdgcn_global_load_lds(
      (const __attribute__((address_space(1))) u32*)g,
      (__attribute__((address_space(3))) u32*)l, 16, 0, 0);
}

// --------------------------- dedup ----------------------------------------
__global__ void dedup_kernel(const int* __restrict__ ridx,
                             unsigned* __restrict__ bitmap,
                             float* __restrict__ keepf) {
  int comp = blockIdx.x;
  for (int l = threadIdx.x; l < MP; l += 256) {
    float kv = 0.0f;
    if (l < LL) {
      int r = ridx[comp * LL + l];
      unsigned bit = 1u << (r & 31);
      unsigned old = atomicOr(&bitmap[(comp << 10) + (r >> 5)], bit);
      kv = (old & bit) ? 0.0f : 1.0f;
    }
    keepf[(comp << 10) + l] = kv;
  }
}

// --------------------------- gather: x rows -> pre-swizzled bf16 -----------
__global__ __launch_bounds__(256) void gather_kernel(
    const float* __restrict__ x, const int* __restrict__ ridx,
    short* __restrict__ Ab) {
  int bid = blockIdx.x;
  int comp = bid >> 7, rgrp = bid & 127;
  int t = threadIdx.x;
  int tr = t >> 5, tn = t & 31;
  int m = rgrp * 8 + tr;
  int mi = m < LL ? m : LL - 1;
  int r = ridx[comp * LL + mi];
  int tokoff = comp >= 16 ? TOKN / 2 : 0;
  const float* src = x + ((size_t)(r >> 11) * TOKN + (r & 2047) + tokoff) * DD;
  short* drow = Ab + ((size_t)(comp * MP + m)) * DD;
  int s_m = swz(m);
#pragma unroll
  for (int i = 0; i < 8; ++i) {
    int gi = tn + 32 * i;
    float4 f0 = *reinterpret_cast<const float4*>(src + gi * 8);
    float4 f1 = *reinterpret_cast<const float4*>(src + gi * 8 + 4);
    bf16x8 pk;
    pk[0]=f2bf(f0.x); pk[1]=f2bf(f0.y); pk[2]=f2bf(f0.z); pk[3]=f2bf(f0.w);
    pk[4]=f2bf(f1.x); pk[5]=f2bf(f1.y); pk[6]=f2bf(f1.z); pk[7]=f2bf(f1.w);
    int c = gi >> 3, g = gi & 7;
    *reinterpret_cast<bf16x8*>(&drow[c * 64 + ((g ^ s_m) << 3)]) = pk;
  }
}

// --------------------------- shared K-loop (single-buffered, 48 KB) --------
// LDS (shorts): Abuf[16384] @0 (256 rows x 64k), Bbuf[8192] @16384.
// Iter t: compute(t); barrier; bwrite B(t+1) [regs]; aglds A(t+1);
// bload B(t+2); lgkm(0); vmcnt(8 | 0 at tail) -> own aglds drained BEFORE
// barrier (cross-wave safe); barrier. Per-block drain hidden by 3 blocks/CU.
template<int LDW>
__device__ __forceinline__ void kloop(
    const short* __restrict__ aBase,   // bf16 pre-swizzled rows, stride 2048
    const float* __restrict__ wBase,   // fp32 W [k][LDW] at col offset nt*BNX
    short* sm, f32x4 (&acc)[8][4],
    int wm, int wn, int lr, int lg, int tid) {
  const short* aSrc0 = aBase + (size_t)(tid >> 3) * 2048 + (tid & 7) * 8;
  int ldsA0 = tid * 8;
  int tn = tid & 31, tkb = tid >> 5, bn0 = tn * 4;
  const float* wCol = wBase + bn0;

  float4 brB[8];

  auto aglds = [&](int t) {
#pragma unroll
    for (int q = 0; q < 8; ++q)
      gl_lds16(aSrc0 + (size_t)q * 65536 + t * 64, sm + ldsA0 + q * 2048);
  };
  auto bload = [&](int t) {
    const float* bb = wCol + (size_t)(t * 64 + tkb * 8) * LDW;
#pragma unroll
    for (int i = 0; i < 8; ++i)
      brB[i] = *reinterpret_cast<const float4*>(bb + (size_t)i * LDW);
  };
  auto bwrite = [&]() {
    short* Bs = sm + 16384;
#pragma unroll
    for (int j = 0; j < 4; ++j) {
      bf16x8 pk;
#pragma unroll
      for (int i = 0; i < 8; ++i) pk[i] = f2bf((&brB[i].x)[j]);
      *reinterpret_cast<bf16x8*>(&Bs[sw(bn0 + j, tkb)]) = pk;
    }
  };
  auto compute = [&]() {
    const short* A = sm;
    const short* B = sm + 16384;
#pragma unroll
    for (int kk = 0; kk < 2; ++kk) {
      bf16x8 af[8], bfr[4];
#pragma unroll
      for (int i = 0; i < 8; ++i)
        af[i] = *reinterpret_cast<const bf16x8*>(&A[sw(wm + i * 16 + lr, kk * 4 + lg)]);
#pragma unroll
      for (int j = 0; j < 4; ++j)
        bfr[j] = *reinterpret_cast<const bf16x8*>(&B[sw(wn + j * 16 + lr, kk * 4 + lg)]);
      __builtin_amdgcn_s_setprio(1);
#pragma unroll
      for (int i = 0; i < 8; ++i)
#pragma unroll
        for (int j = 0; j < 4; ++j)
          acc[i][j] = __builtin_amdgcn_mfma_f32_16x16x32_bf16(af[i], bfr[j], acc[i][j], 0, 0, 0);
      __builtin_amdgcn_s_setprio(0);
    }
  };

  // prologue: B(0) regs -> Bbuf; A(0) glds; B(1) regs; full drain; barrier.
  bload(0);
  aglds(0);
  bwrite();                 // compiler waits bload(0) (aglds may overlap)
  bload(1);
  asm volatile("s_waitcnt vmcnt(0) lgkmcnt(0)" ::: "memory");
  __builtin_amdgcn_s_barrier();

#pragma unroll 1
  for (int t = 0; t < NT; ++t) {
    compute();
    __builtin_amdgcn_s_barrier();          // all waves done reading A(t), B(t)
    if (t + 1 < NT) {
      bwrite();                            // B(t+1) -> Bbuf (regs valid)
      aglds(t + 1);                        // A(t+1) -> Abuf (readers done)
      if (t + 2 < NT) {
        bload(t + 2);                      // newest 8: stays in flight
        asm volatile("s_waitcnt lgkmcnt(0)" ::: "memory");
        asm volatile("s_waitcnt vmcnt(8)" ::: "memory");   // aglds(t+1) done
      } else {
        asm volatile("s_waitcnt vmcnt(0) lgkmcnt(0)" ::: "memory");
      }
      __builtin_amdgcn_s_barrier();        // cross-wave: staging visible
    }
  }
}

// --------------------------- GEMM1: h = gelu(x_sel @ W1 + b1) --------------
__global__ __launch_bounds__(256, 2) void gemm1_kernel(
    const float* __restrict__ nW1, const float* __restrict__ nb1,
    const float* __restrict__ eW1, const float* __restrict__ eb1,
    const short* __restrict__ Ab, short* __restrict__ hbuf) {
  __shared__ short smem[24576];   // 48 KB -> 3 blocks/CU (VGPR 128 allows 4)

  constexpr int NWG = NCOMP * MTX * NT1;   // 2048
  constexpr int CPX = NWG / 8;
  int b0 = blockIdx.x;
  int lb = (b0 & 7) * CPX + (b0 >> 3);     // XCD-chunked (T1), bijective
  int comp = lb / (MTX * NT1);
  int rem  = lb % (MTX * NT1);
  int mt = rem / NT1, nt = rem % NT1;
  bool isEdge = comp >= 16;
  int k16 = isEdge ? comp - 16 : comp;
  const float* W1 = (isEdge ? eW1 : nW1) + (size_t)k16 * DD * HH;
  const float* b1 = (isEdge ? eb1 : nb1) + (size_t)k16 * HH;

  int tid = threadIdx.x, lane = tid & 63, wid = tid >> 6;
  int wm = (wid >> 1) << 7, wn = (wid & 1) << 6;   // 2x2 waves of 128x64
  int lr = lane & 15, lg = lane >> 4;

  f32x4 acc[8][4] = {};
  kloop<HH>(Ab + ((size_t)(comp * MP + mt * BMX)) * DD,
            W1 + nt * BNX, smem, acc, wm, wn, lr, lg, tid);

  // epilogue: +b1, exact gelu; two 128-row phases through a 33 KB Cs
  // (stride 132), then coalesced PRE-SWIZZLED bf16 h store.
  __builtin_amdgcn_s_barrier();
  short* Cs = smem;                        // 128*132 = 16896 shorts (33 KB)
  const float* b1p = b1 + nt * BNX;
#pragma unroll 1
  for (int p = 0; p < 2; ++p) {
    if ((wm >> 7) == p) {                  // waves owning rows p*128..+127
#pragma unroll
      for (int i = 0; i < 8; ++i)
#pragma unroll
        for (int j = 0; j < 4; ++j) {
          int nl = wn + j * 16 + lr;
          float bias = b1p[nl];
#pragma unroll
          for (int rr = 0; rr < 4; ++rr) {
            int r = i * 16 + lg * 4 + rr;  // 0..127 within phase
            float v = acc[i][j][rr] + bias;
            float ge = 0.5f * v * (1.0f + erff(v * 0.70710678118654752f));
            Cs[r * 132 + nl] = f2bf(ge);
          }
        }
    }
    __syncthreads();
    short* hrow = hbuf + ((size_t)(comp * MP + mt * BMX + p * 128)) * HH;
#pragma unroll
    for (int q = 0; q < 16; ++q) {
      int gl = q * 256 + tid;
      int r = gl >> 5, gg = gl & 31;       // 32 4-short granules per row
      s16x4 v = *reinterpret_cast<const s16x4*>(&Cs[r * 132 + gg * 4]);
      int dst = (nt * 2 + (gg >> 4)) * 64 + ((((gg >> 1) & 7) ^ swz(r)) << 3) + (gg & 1) * 4;
      *reinterpret_cast<s16x4*>(&hrow[(size_t)r * HH + dst]) = v;
    }
    __syncthreads();
  }
}

// --------------------------- GEMM2: o = h @ W2 + b2, masked seg-reduce -----
__global__ __launch_bounds__(256, 2) void gemm2_kernel(
    const short* __restrict__ hbuf, const int* __restrict__ ridx,
    const float* __restrict__ nW2, const float* __restrict__ nb2,
    const float* __restrict__ eW2, const float* __restrict__ eb2,
    const float* __restrict__ keepf, float* __restrict__ partial) {
  __shared__ short smem[24576];   // 48 KB

  constexpr int NWG = NCOMP * MTX * NT2;   // 1024
  constexpr int CPX = NWG / 8;
  int b0 = blockIdx.x;
  int lb = (b0 & 7) * CPX + (b0 >> 3);
  int comp = lb / (MTX * NT2);
  int rem  = lb % (MTX * NT2);
  int mt = rem / NT2, nt = rem % NT2;
  bool isEdge = comp >= 16;
  int k16 = isEdge ? comp - 16 : comp;
  const float* W2 = (isEdge ? eW2 : nW2) + (size_t)k16 * HH * CC;
  const float* b2 = (isEdge ? eb2 : nb2) + (size_t)k16 * CC;

  int tid = threadIdx.x, lane = tid & 63, wid = tid >> 6;
  int wm = (wid >> 1) << 7, wn = (wid & 1) << 6;
  int lr = lane & 15, lg = lane >> 4;

  f32x4 acc[8][4] = {};
  kloop<CC>(hbuf + ((size_t)(comp * MP + mt * BMX)) * HH,
            W2 + nt * BNX, smem, acc, wm, wn, lr, lg, tid);

  // epilogue: (+b2) * keep, seg-reduce 256 rows by timestamp.
  // part stride 257 (257%32==1): t spreads across banks; no deterministic
  // same-bank atomicAdd pileups.
  __builtin_amdgcn_s_barrier();
  float* part = (float*)smem;                     // 16*257 floats = 16.4 KB
  int*   tarr = (int*)((char*)smem + 16640);      // 256 ints
  float* karr = (float*)((char*)smem + 17664);    // 256 floats
  if (tid < BMX) {
    int mglob = mt * BMX + tid;
    int mi = mglob < LL ? mglob : LL - 1;
    int r2 = ridx[comp * LL + mi];
    tarr[tid] = r2 >> 11;
    karr[tid] = keepf[(comp << 10) + mglob];      // 0 for padded/dup rows
  }
  for (int e = tid; e < TT * 257; e += 256) part[e] = 0.0f;
  __syncthreads();
  const float* b2p = b2 + nt * BNX;
#pragma unroll
  for (int i = 0; i < 8; ++i)
#pragma unroll
    for (int j = 0; j < 4; ++j) {
      int nl = wn + j * 16 + lr;
      float bias = b2p[nl];
#pragma unroll
      for (int rr = 0; rr < 4; ++rr) {
        int ml = wm + i * 16 + lg * 4 + rr;
        float v = (acc[i][j][rr] + bias) * karr[ml];
        atomicAdd(&part[tarr[ml] * 257 + nl], v);
      }
    }
  __syncthreads();
  float* pout = partial + ((size_t)(comp * MTX + mt)) * TT * CC + nt * BNX;
  for (int e = tid; e < TT * BNX; e += 256) {
    int t2 = e >> 7, c = e & 127;
    pout[(size_t)t2 * CC + c] = part[t2 * 257 + c];
  }
}

// --------------------------- final reduce over m-tiles ---------------------
__global__ void reduce_kernel(const float* __restrict__ partial,
                              float* __restrict__ out) {
  int idx = blockIdx.x * 256 + threadIdx.x;
  int c    = idx & (CC - 1);
  int comp = (idx >> 10) & (NCOMP - 1);
  int t    = idx >> 15;
  float s = 0.0f;
#pragma unroll
  for (int mt = 0; mt < MTX; ++mt)
    s += partial[(((size_t)(comp * MTX + mt)) * TT + t) * CC + c];
  out[idx] = s * (1.0f / 4096.0f);
}

// ---------------------------------------------------------------------------
extern "C" void kernel_launch(void* const* d_in, const int* in_sizes, int n_in,
                              void* d_out, int out_size, void* d_ws, size_t ws_size,
                              hipStream_t stream) {
  const float* x    = (const float*)d_in[0];
  const int*   ridx = (const int*)d_in[3];
  const float* nW1  = (const float*)d_in[4];
  const float* nb1  = (const float*)d_in[5];
  const float* nW2  = (const float*)d_in[6];
  const float* nb2  = (const float*)d_in[7];
  const float* eW1  = (const float*)d_in[8];
  const float* eb1  = (const float*)d_in[9];
  const float* eW2  = (const float*)d_in[10];
  const float* eb2  = (const float*)d_in[11];
  float* out = (float*)d_out;

  // ws: [h 134MB][bitmap][keep][partial 8.4MB][Ab 134MB]  ~277 MB
  const size_t H_B   = (size_t)NCOMP * MP * HH * 2;
  const size_t BMP_B = (size_t)NCOMP * 1024 * 4;
  const size_t KP_B  = (size_t)NCOMP * 1024 * 4;
  const size_t PRT_B = (size_t)NCOMP * MTX * TT * CC * 4;
  const size_t base  = H_B + BMP_B + KP_B + PRT_B;

  char* ws = (char*)d_ws;
  short* hbuf      = (short*)ws;
  unsigned* bitmap = (unsigned*)(ws + H_B);
  float* keepf     = (float*)(ws + H_B + BMP_B);
  float* partial   = (float*)(ws + H_B + BMP_B + KP_B);
  short* Ab        = (short*)(ws + base);

  hipMemsetAsync(bitmap, 0, BMP_B, stream);
  dedup_kernel<<<NCOMP, 256, 0, stream>>>(ridx, bitmap, keepf);
  gather_kernel<<<NCOMP * 128, 256, 0, stream>>>(x, ridx, Ab);
  gemm1_kernel<<<NCOMP * MTX * NT1, 256, 0, stream>>>(nW1, nb1, eW1, eb1, Ab, hbuf);
  gemm2_kernel<<<NCOMP * MTX * NT2, 256, 0, stream>>>(hbuf, ridx, nW2, nb2, eW2, eb2, keepf, partial);
  reduce_kernel<<<out_size / 256, 256, 0, stream>>>(partial, out);
}